// Round 1
// baseline (2278.409 us; speedup 1.0000x reference)
//
#include <hip/hip_runtime.h>

#define HH 4  // heads

// ---------- helpers: order-preserving float<->uint encoding for atomic max ----------
__device__ __forceinline__ unsigned fenc(float f) {
    unsigned u = __float_as_uint(f);
    return (u & 0x80000000u) ? ~u : (u | 0x80000000u);
}
__device__ __forceinline__ float fdec(unsigned u) {
    return __uint_as_float((u & 0x80000000u) ? (u ^ 0x80000000u) : ~u);
}

// ---------- GEMM: f[row, :] = (relu?)x[row, :128] @ W[128, KOUT] ----------
template <int KOUT, int TPB>
__global__ void gemm_kernel(const float* __restrict__ x, const float* __restrict__ W,
                            float* __restrict__ f, int relu_in) {
    __shared__ float xs[128];
    const int row = blockIdx.x;
    if (threadIdx.x < 128) {
        float v = x[row * 128 + threadIdx.x];
        if (relu_in) v = fmaxf(v, 0.0f);
        xs[threadIdx.x] = v;
    }
    __syncthreads();
    constexpr int CPT = KOUT / TPB;  // cols per thread
    float acc[CPT];
#pragma unroll
    for (int j = 0; j < CPT; ++j) acc[j] = 0.0f;
    for (int k = 0; k < 128; ++k) {
        const float xv = xs[k];
#pragma unroll
        for (int j = 0; j < CPT; ++j)
            acc[j] = fmaf(xv, W[k * KOUT + threadIdx.x + j * TPB], acc[j]);
    }
#pragma unroll
    for (int j = 0; j < CPT; ++j) f[row * KOUT + threadIdx.x + j * TPB] = acc[j];
}

// ---------- el/er: el[n,h] = sum_c f[n,h,c]*al[h,c] ----------
template <int C>
__global__ void elr_kernel(const float* __restrict__ f, const float* __restrict__ al,
                           const float* __restrict__ ar, float* __restrict__ el,
                           float* __restrict__ er, int nh) {
    int idx = blockIdx.x * blockDim.x + threadIdx.x;
    if (idx >= nh) return;
    int node = idx / HH, h = idx % HH;
    const float* fp = f + node * (HH * C) + h * C;
    float sl = 0.0f, sr = 0.0f;
    for (int c = 0; c < C; ++c) {
        float v = fp[c];
        sl = fmaf(v, al[h * C + c], sl);
        sr = fmaf(v, ar[h * C + c], sr);
    }
    el[idx] = sl;
    er[idx] = sr;
}

// ---------- edge pass A: score + segment max ----------
__global__ void edge_score(const int* __restrict__ src, const int* __restrict__ dst,
                           const float* __restrict__ el, const float* __restrict__ er,
                           float* __restrict__ ea, unsigned* __restrict__ menc, int E) {
    int i = blockIdx.x * blockDim.x + threadIdx.x;
    if (i >= E) return;
    int s = src[i], d = dst[i];
#pragma unroll
    for (int h = 0; h < HH; ++h) {
        float v = el[s * HH + h] + er[d * HH + h];
        v = (v >= 0.0f) ? v : 0.2f * v;  // leaky relu, slope 0.2
        ea[i * HH + h] = v;
        atomicMax(&menc[d * HH + h], fenc(v));
    }
}

// ---------- edge pass B: exp(e - m[dst]) + segment sum ----------
__global__ void edge_exp(const int* __restrict__ dst, const unsigned* __restrict__ menc,
                         float* __restrict__ ea, float* __restrict__ z, int E) {
    int i = blockIdx.x * blockDim.x + threadIdx.x;
    if (i >= E) return;
    int d = dst[i];
#pragma unroll
    for (int h = 0; h < HH; ++h) {
        float m = fdec(menc[d * HH + h]);
        float a = expf(ea[i * HH + h] - m);
        ea[i * HH + h] = a;
        atomicAdd(&z[d * HH + h], a);
    }
}

// ---------- edge pass B2: alpha = a / z[dst] ----------
__global__ void edge_alpha(const int* __restrict__ dst, float* __restrict__ ea,
                           const float* __restrict__ z, int E4) {
    int i = blockIdx.x * blockDim.x + threadIdx.x;
    if (i >= E4) return;
    int e = i >> 2, h = i & 3;
    ea[i] = ea[i] / z[dst[e] * HH + h];
}

// ---------- edge pass C: out[dst, k] += alpha * f[src, k] ----------
template <int K>
__global__ void edge_aggr(const int* __restrict__ src, const int* __restrict__ dst,
                          const float* __restrict__ ea, const float* __restrict__ f,
                          float* __restrict__ out, int E) {
    constexpr int CH = K / HH;  // channels per head
    const int total = E * K;
    for (int idx = blockIdx.x * blockDim.x + threadIdx.x; idx < total;
         idx += gridDim.x * blockDim.x) {
        int e = idx / K;
        int k = idx - e * K;
        int h = k / CH;
        int s = src[e], d = dst[e];
        float alpha = ea[e * HH + h];
        atomicAdd(&out[d * K + k], alpha * f[s * K + k]);
    }
}

// ---------- global max pool (with relu) over nodes ----------
__global__ void pool_kernel(const float* __restrict__ o, unsigned* __restrict__ pooled, int n) {
    const int col = threadIdx.x;  // 512 threads
    float m = 0.0f;
    for (int r = blockIdx.x; r < n; r += gridDim.x) m = fmaxf(m, o[(size_t)r * 512 + col]);
    m = fmaxf(m, 0.0f);  // relu (also pool identity is fine since relu>=0)
    atomicMax(&pooled[col], __float_as_uint(m));  // nonneg floats: uint order == float order
}

// ---------- FC head + softmax ----------
__global__ void head_kernel(const float* __restrict__ pooled, const float* __restrict__ fcw,
                            const float* __restrict__ fcb, float* __restrict__ out) {
    __shared__ float logits[8];
    int t = threadIdx.x;
    if (t < 8) {
        float acc = fcb[t];
        for (int i = 0; i < 512; ++i) acc = fmaf(pooled[i], fcw[i * 8 + t], acc);
        logits[t] = acc;
    }
    __syncthreads();
    if (t == 0) {
        float mx = -1e30f;
        for (int j = 0; j < 8; ++j) mx = fmaxf(mx, logits[j]);
        float ex[8], s = 0.0f;
        for (int j = 0; j < 8; ++j) { ex[j] = expf(logits[j] - mx); s += ex[j]; }
        for (int j = 0; j < 8; ++j) out[j] = ex[j] / s;
    }
}

extern "C" void kernel_launch(void* const* d_in, const int* in_sizes, int n_in,
                              void* d_out, int out_size, void* d_ws, size_t ws_size,
                              hipStream_t stream) {
    const float* x0  = (const float*)d_in[0];
    const int*   src = (const int*)d_in[1];
    const int*   dst = (const int*)d_in[2];
    const float* W0  = (const float*)d_in[3];
    const float* al0 = (const float*)d_in[4];
    const float* ar0 = (const float*)d_in[5];
    const float* W1  = (const float*)d_in[6];
    const float* al1 = (const float*)d_in[7];
    const float* ar1 = (const float*)d_in[8];
    const float* W2  = (const float*)d_in[9];
    const float* al2 = (const float*)d_in[10];
    const float* ar2 = (const float*)d_in[11];
    const float* fcw = (const float*)d_in[12];
    const float* fcb = (const float*)d_in[13];
    float* outp = (float*)d_out;

    const int N = in_sizes[0] / 128;
    const int E = in_sizes[1];

    // workspace layout (floats)
    float* F  = (float*)d_ws;                 // N*512  projected features
    float* OA = F + (size_t)N * 512;          // N*512  output accum A
    float* OB = OA + (size_t)N * 512;         // N*128  output accum B
    float* EA = OB + (size_t)N * 128;         // E*4    edge scores / alpha
    float* el = EA + (size_t)E * HH;          // N*4
    float* er = el + (size_t)N * HH;          // N*4
    float* z  = er + (size_t)N * HH;          // N*4
    unsigned* menc = (unsigned*)(z + (size_t)N * HH);  // N*4
    float* pooled  = (float*)(menc + (size_t)N * HH);  // 512

    auto run_layer = [&](const float* x, int relu_in, const float* W, const float* al,
                         const float* ar, int K, float* obuf) {
        hipMemsetAsync(z, 0, (size_t)N * HH * sizeof(float), stream);
        hipMemsetAsync(menc, 0, (size_t)N * HH * sizeof(unsigned), stream);
        hipMemsetAsync(obuf, 0, (size_t)N * K * sizeof(float), stream);
        const int nh = N * HH;
        if (K == 128) {
            gemm_kernel<128, 128><<<N, 128, 0, stream>>>(x, W, F, relu_in);
            elr_kernel<32><<<(nh + 255) / 256, 256, 0, stream>>>(F, al, ar, el, er, nh);
        } else {
            gemm_kernel<512, 256><<<N, 256, 0, stream>>>(x, W, F, relu_in);
            elr_kernel<128><<<(nh + 255) / 256, 256, 0, stream>>>(F, al, ar, el, er, nh);
        }
        edge_score<<<(E + 255) / 256, 256, 0, stream>>>(src, dst, el, er, EA, menc, E);
        edge_exp<<<(E + 255) / 256, 256, 0, stream>>>(dst, menc, EA, z, E);
        edge_alpha<<<(E * HH + 255) / 256, 256, 0, stream>>>(dst, EA, z, E * HH);
        if (K == 128)
            edge_aggr<128><<<2048, 256, 0, stream>>>(src, dst, EA, F, obuf, E);
        else
            edge_aggr<512><<<4096, 256, 0, stream>>>(src, dst, EA, F, obuf, E);
    };

    run_layer(x0, 0, W0, al0, ar0, 128, OA);   // layer 0: out -> OA (N*128 used)
    run_layer(OA, 1, W1, al1, ar1, 128, OB);   // layer 1: out -> OB
    run_layer(OB, 1, W2, al2, ar2, 512, OA);   // layer 2: out -> OA (N*512)

    hipMemsetAsync(pooled, 0, 512 * sizeof(float), stream);
    pool_kernel<<<256, 512, 0, stream>>>(OA, (unsigned*)pooled, N);
    head_kernel<<<1, 64, 0, stream>>>(pooled, fcw, fcb, outp);
}